// Round 8
// baseline (1602.553 us; speedup 1.0000x reference)
//
#include <hip/hip_runtime.h>
#include <hip/hip_bf16.h>

// Problem constants (F is hard-coded 31 in the reference / TAG)
#define FDIM 31
#define FPAD 32      // padded row length in elements
#define RSTRIDE 16   // row stride in uints (32 bf16 = 64 B = 16 uints = 1 cache line)

// Coarse bucketing for CSR build: 2048 nodes per bucket
#define CBITS 11
#define CW    (1 << CBITS)
#define MAXBUK 256
#define TILE 4096

// clang ext-vector types: required by __builtin_nontemporal_{load,store}
// (HIP_vector_type int4/uint4 pointers are rejected by the builtin).
typedef int      iv4 __attribute__((ext_vector_type(4)));
typedef unsigned uv4 __attribute__((ext_vector_type(4)));

// ---- bf16 pack/unpack helpers (packed as 2 bf16 per uint, little-endian)
__device__ __forceinline__ float bf_lo(unsigned u) { return __uint_as_float(u << 16); }
__device__ __forceinline__ float bf_hi(unsigned u) { return __uint_as_float(u & 0xFFFF0000u); }
__device__ __forceinline__ unsigned pack2(float lo, float hi) {
    unsigned a = __float_as_uint(lo), b = __float_as_uint(hi);
    unsigned ra = (a + 0x7FFFu + ((a >> 16) & 1u)) >> 16;   // RNE
    unsigned rb = (b + 0x7FFFu + ((b >> 16) & 1u)) >> 16;
    return ra | (rb << 16);
}

// first index in sorted gid[0..Ntot) with gid[idx] >= g
__device__ __forceinline__ int lb_gid(const int* __restrict__ gid, int Ntot, int g) {
    int lo = 0, hi = Ntot;
    while (lo < hi) { int mid = (lo + hi) >> 1; if (gid[mid] < g) lo = mid + 1; else hi = mid; }
    return lo;
}

// --------------------------------------------------- multisplit (level 1)
// R8 v2: direct-write. LDS cursors are pre-offset to each bucket's global
// base, so pass 2 writes bucketed[] immediately -- the ordered[] staging pass
// and the per-edge binary search are gone. Within-bucket order is arbitrary
// (bucket_build re-histograms, so any order is correct). Same-line writes
// from one wave coalesce in the TA; HBM writes stay ~E*4B via L2 write-back.
__global__ __launch_bounds__(256) void multisplit_kernel(
    const int* __restrict__ src, const int* __restrict__ dst,
    int* __restrict__ gcnt, int* __restrict__ bucketed,
    int cap, int E, int nbuk)
{
    __shared__ int hist[MAXBUK];
    __shared__ int cur[MAXBUK];
    const int tid = threadIdx.x;
    const int e0 = blockIdx.x * TILE;
    const int n = min(TILE, E - e0);
    if (tid < MAXBUK) hist[tid] = 0;
    __syncthreads();
    for (int i = tid; i < n; i += 256)
        atomicAdd(&hist[dst[e0 + i] >> CBITS], 1);
    __syncthreads();
    if (tid < nbuk) {
        int h = hist[tid];
        cur[tid] = h ? atomicAdd(&gcnt[tid], h) : 0;   // global base for this tile
    }
    __syncthreads();
    for (int i = tid; i < n; i += 256) {
        int s = src[e0 + i], d = dst[e0 + i];
        int b = d >> CBITS;
        int pos = atomicAdd(&cur[b], 1);               // bucket-global slot
        if (pos < cap) bucketed[(size_t)b * cap + pos] = (s << CBITS) | (d & (CW - 1));
    }
}

// ---------------------------------- small scans: num->soff, gcnt->bbase
// R8: wave-parallel chunked __shfl_up scans (the 1-thread serial loops cost
// ~200 L2-latency-bound iterations). 64-thread block = 1 wave.
__global__ __launch_bounds__(64) void small_scans_kernel(
    const int* __restrict__ num, int* __restrict__ soff, int Bn,
    const int* __restrict__ gcnt, int* __restrict__ bbase, int nbuk, int cap) {
    const int t = threadIdx.x;
    __shared__ int carry;
    if (t == 0) { carry = 0; soff[0] = 0; }
    __syncthreads();
    for (int c0 = 0; c0 < Bn; c0 += 64) {
        int idx = c0 + t;
        int v = (idx < Bn) ? num[idx] : 0;
        int sc = v;
#pragma unroll
        for (int o = 1; o < 64; o <<= 1) { int u = __shfl_up(sc, o); if (t >= o) sc += u; }
        if (idx < Bn) soff[idx + 1] = carry + sc;      // inclusive
        __syncthreads();
        if (t == 63) carry += sc;
        __syncthreads();
    }
    if (t == 0) carry = 0;
    __syncthreads();
    for (int c0 = 0; c0 < nbuk; c0 += 64) {
        int idx = c0 + t;
        int v = (idx < nbuk) ? (((min(gcnt[idx], cap) + 7) & ~7) + 7 * CW) : 0;
        int sc = v;
#pragma unroll
        for (int o = 1; o < 64; o <<= 1) { int u = __shfl_up(sc, o); if (t >= o) sc += u; }
        if (idx < nbuk) bbase[idx] = carry + sc - v;   // exclusive
        __syncthreads();
        if (t == 63) carry += sc;
        __syncthreads();
    }
}

// ------ per-bucket: hist + LDS scan + rowbeg/rowend/normv + CSR fill + CAST
// Rows are padded to a multiple of 8 edges; pad slots point at dummy node N
// (whose feature row is all zeros) so the SpMM loop has NO scalar tail.
// R8: the fp32->bf16 norm-scaled cast of x into HA is fused here (one less
// launch; normv stays in LDS, no global round-trip).
__global__ __launch_bounds__(1024) void bucket_build_kernel(
    const int* __restrict__ bucketed, const int* __restrict__ gcnt,
    const int* __restrict__ bbase,
    int* __restrict__ rowbeg, int* __restrict__ rowend,
    float* __restrict__ normv, float* __restrict__ invn,
    int* __restrict__ col,
    const float* __restrict__ x, unsigned* __restrict__ HA,
    int cap, int N, int nbuk)
{
    __shared__ int hist[CW];     // counts -> padded counts -> inclusive scan
    __shared__ int lcur[CW];     // fill cursors
    __shared__ float nvL[CW];    // norm values for the fused cast
    const int b = blockIdx.x, tid = threadIdx.x;
    hist[tid] = 0; hist[tid + 1024] = 0;
    __syncthreads();
    const int cnt = min(gcnt[b], cap);
    const int* reg = bucketed + (size_t)b * cap;
    for (int i = tid; i < cnt; i += 1024)
        atomicAdd(&hist[reg[i] & (CW - 1)], 1);
    __syncthreads();
    int c0 = hist[tid], c1 = hist[tid + 1024];       // real per-node counts
    int p0 = (c0 + 7) & ~7, p1 = (c1 + 7) & ~7;      // padded to multiple of 8
    __syncthreads();
    hist[tid] = p0; hist[tid + 1024] = p1;           // scan PADDED counts
    __syncthreads();
    // Hillis-Steele inclusive scan over 2048 entries with 1024 threads
    for (int off = 1; off < CW; off <<= 1) {
        int a0 = (tid >= off) ? hist[tid - off] : 0;
        int a1 = (tid + 1024 >= off) ? hist[tid + 1024 - off] : 0;
        __syncthreads();
        hist[tid] += a0; hist[tid + 1024] += a1;
        __syncthreads();
    }
    const int base = bbase[b];
    const int base_node = b << CBITS;
    int r0 = -1, r1 = -1;
    int node = base_node + tid;
    if (node < N) {
        r0 = base + hist[tid] - p0;                  // exclusive padded prefix
        rowbeg[node] = r0; rowend[node] = r0 + p0; lcur[tid] = r0;
        int cr = c0 > 0 ? c0 : 1;
        float nv = rsqrtf((float)cr);
        normv[node] = nv; nvL[tid] = nv;
        invn[node]  = sqrtf((float)cr);
    }
    node = base_node + tid + 1024;
    if (node < N) {
        r1 = base + hist[tid + 1024] - p1;
        rowbeg[node] = r1; rowend[node] = r1 + p1; lcur[tid + 1024] = r1;
        int cr = c1 > 0 ? c1 : 1;
        float nv = rsqrtf((float)cr);
        normv[node] = nv; nvL[tid + 1024] = nv;
        invn[node]  = sqrtf((float)cr);
    }
    __syncthreads();
    for (int i = tid; i < cnt; i += 1024) {
        int e = reg[i];
        int p = atomicAdd(&lcur[e & (CW - 1)], 1);
        col[p] = e >> CBITS;
    }
    // pad slots -> dummy node N (disjoint from real slots: no sync needed)
    if (r0 >= 0) for (int j = r0 + c0; j < r0 + p0; ++j) col[j] = N;
    if (r1 >= 0) for (int j = r1 + c1; j < r1 + p1; ++j) col[j] = N;
    // ---- fused cast: HA[n] = bf16(norm[n] * x[n]) for this bucket's nodes
    // (row N, if in range, is written as zeros -- the pad-gather target)
    __syncthreads();                                 // nvL ready
    const int nodes_here = min(CW, N + 1 - base_node);
    for (int idx = tid; idx < nodes_here * RSTRIDE; idx += 1024) {
        int loc = idx >> 4, q = idx & 15;
        int nodec = base_node + loc;
        unsigned val = 0u;
        if (nodec < N) {
            float nv = nvL[loc];
            int f0 = 2 * q, f1 = 2 * q + 1;
            float lo = (f0 < FDIM) ? nv * x[(size_t)nodec * FDIM + f0] : 0.0f;
            float hi = (f1 < FDIM) ? nv * x[(size_t)nodec * FDIM + f1] : 0.0f;
            val = pack2(lo, hi);
        }
        HA[(size_t)nodec * RSTRIDE + q] = val;
    }
    // safety: if N is a multiple of CW, row N belongs to no bucket
    if (b == nbuk - 1 && base_node + CW <= N)
        for (int q = tid; q < RSTRIDE; q += 1024) HA[(size_t)N * RSTRIDE + q] = 0u;
}

// ---- gather/accumulate macro bodies
#define GATHER8(HSRC, r0, r1, r2, r3, r4, r5, r6, r7, CA, CB)                    \
    r0 = *((const uint4*)(HSRC + (size_t)(CA).x * RSTRIDE) + sub);               \
    r1 = *((const uint4*)(HSRC + (size_t)(CA).y * RSTRIDE) + sub);               \
    r2 = *((const uint4*)(HSRC + (size_t)(CA).z * RSTRIDE) + sub);               \
    r3 = *((const uint4*)(HSRC + (size_t)(CA).w * RSTRIDE) + sub);               \
    r4 = *((const uint4*)(HSRC + (size_t)(CB).x * RSTRIDE) + sub);               \
    r5 = *((const uint4*)(HSRC + (size_t)(CB).y * RSTRIDE) + sub);               \
    r6 = *((const uint4*)(HSRC + (size_t)(CB).z * RSTRIDE) + sub);               \
    r7 = *((const uint4*)(HSRC + (size_t)(CB).w * RSTRIDE) + sub);

#define ACC_EDGE(vN)                                                   \
    acc0 += bf_lo(vN.x); acc1 += bf_hi(vN.x);                          \
    acc2 += bf_lo(vN.y); acc3 += bf_hi(vN.y);                          \
    acc4 += bf_lo(vN.z); acc5 += bf_hi(vN.z);                          \
    acc6 += bf_lo(vN.w); acc7 += bf_hi(vN.w);

#define ACC8(r0, r1, r2, r3, r4, r5, r6, r7)                           \
    ACC_EDGE(r0) ACC_EDGE(r1) ACC_EDGE(r2) ACC_EDGE(r3)                \
    ACC_EDGE(r4) ACC_EDGE(r5) ACC_EDGE(r6) ACC_EDGE(r7)

// ------------------------------------------------------------------ SpMM hop1
// Storage invariant: Hin rows are norm-scaled (H~ = norm .* h), so a hop is
// H~out = norm^2 .* sum(H~in[col]). Rows padded to x8 with dummy node N.
// NOTE (R3/R7 post-mortems): the random gather runs at a ~3.4-3.7 TB/s
// fabric ceiling insensitive to occupancy (47->55%: null), deeper per-wave
// pipelining (2-deep: null), and store cache policy (NT vs normal: null).
// ~113 us is this kernel's floor without a bytes reduction.
__global__ __launch_bounds__(256) void spmm_kernel(const unsigned* __restrict__ Hin,
                                                   unsigned* __restrict__ Hout,
                                                   const int* __restrict__ rowbeg,
                                                   const int* __restrict__ rowend,
                                                   const int* __restrict__ col,
                                                   const float* __restrict__ normv, int N) {
    int node = blockIdx.x * 64 + (threadIdx.x >> 2);
    int sub = threadIdx.x & 3;
    if (node > N) return;
    if (node == N) {                       // dummy zero row consumed by pad edges
        uint4 z; z.x = z.y = z.z = z.w = 0u;
        *((uint4*)(Hout + (size_t)N * RSTRIDE) + sub) = z;
        return;
    }
    int s = rowbeg[node];
    int nit = (rowend[node] - s) >> 3;
    float acc0 = 0.f, acc1 = 0.f, acc2 = 0.f, acc3 = 0.f;
    float acc4 = 0.f, acc5 = 0.f, acc6 = 0.f, acc7 = 0.f;
    if (nit > 0) {
        const iv4* cl = (const iv4*)(col + s);      // 16B-aligned (rows 8-aligned)
        iv4 ca = __builtin_nontemporal_load(cl);
        iv4 cb = __builtin_nontemporal_load(cl + 1);
        for (int it = 0; it < nit; ++it) {
            uint4 v0, v1, v2, v3, v4, v5, v6, v7;
            GATHER8(Hin, v0, v1, v2, v3, v4, v5, v6, v7, ca, cb)
            const iv4* nx = cl + ((it + 1 < nit) ? 2 : 0);
            iv4 na = __builtin_nontemporal_load(nx);
            iv4 nb = __builtin_nontemporal_load(nx + 1);
            cl += 2;
            ACC8(v0, v1, v2, v3, v4, v5, v6, v7)
            ca = na; cb = nb;
        }
    }
    float nv = normv[node];
    float nn2 = nv * nv;                   // H~out = norm^2 * sum
    uint4 o;
    o.x = pack2(nn2 * acc0, nn2 * acc1);
    o.y = pack2(nn2 * acc2, nn2 * acc3);
    o.z = pack2(nn2 * acc4, nn2 * acc5);
    o.w = pack2(nn2 * acc6, nn2 * acc7);
    *((uint4*)(Hout + (size_t)node * RSTRIDE) + sub) = o;
}

// ---- phase-B workers. JB/NJ are TEMPLATE LITERALS so every W/bias/w_gate
// index is a compile-time offset from a uniform pointer -> provably uniform
// -> s_load. (R5 post-mortem: runtime readfirstlane + clamp broke uniformity
// analysis -> per-lane VMEM W loads -> VALU x2, gather BW -33%.)
// R7 split: mlp_pre (ha.W0 + hb.W1 -- independent of the gather) runs BEFORE
// the barrier, overlapping other waves' gathers; mlp_fin (hc.W2 + epilogue)
// is the only post-barrier work (~1/3 of the FMAs).
template<int JB, int NJ>
__device__ __forceinline__ void mlp_pre(const uint4 (&ra)[4], const uint4 (&rb)[4],
                                        const float* __restrict__ W, float (&out)[8]) {
    const unsigned* ru = (const unsigned*)ra;
    const unsigned* rv = (const unsigned*)rb;
#pragma unroll
    for (int i = 0; i < FDIM; ++i) {
        float va = (i & 1) ? bf_hi(ru[i >> 1]) : bf_lo(ru[i >> 1]);
        float vb = (i & 1) ? bf_hi(rv[i >> 1]) : bf_lo(rv[i >> 1]);
#pragma unroll
        for (int jj = 0; jj < NJ; ++jj) {
            out[jj] = fmaf(va, W[i * FDIM + JB + jj], out[jj]);
            out[jj] = fmaf(vb, W[FDIM * FDIM + i * FDIM + JB + jj], out[jj]);
        }
    }
}

template<int JB, int NJ>
__device__ __forceinline__ void mlp_fin(float (&out)[8], const float* hp,
                                        const float* __restrict__ W,
                                        const float* __restrict__ bias,
                                        float inv, float sc, unsigned* orow,
                                        const float* __restrict__ w_gate,
                                        int do_gate, float& gp) {
#pragma unroll
    for (int i = 0; i < FDIM; ++i) {
        float v = hp[i];
#pragma unroll
        for (int jj = 0; jj < NJ; ++jj)
            out[jj] = fmaf(v, W[2 * FDIM * FDIM + i * FDIM + JB + jj], out[jj]);
    }
#pragma unroll
    for (int jj = 0; jj < NJ; ++jj)
        out[jj] = fmaxf(fmaf(out[jj], inv, bias[JB + jj]), 0.0f);
#pragma unroll
    for (int jj = NJ; jj < 8; ++jj) out[jj] = 0.0f;  // pad column (wave 3)
    uint4 q;
    q.x = pack2(sc * out[0], sc * out[1]);
    q.y = pack2(sc * out[2], sc * out[3]);
    q.z = pack2(sc * out[4], sc * out[5]);
    q.w = pack2(sc * out[6], sc * out[7]);
    ((uint4*)orow)[JB >> 3] = q;                     // disjoint 16B quarter
    if (do_gate) {
#pragma unroll
        for (int jj = 0; jj < NJ; ++jj)
            gp = fmaf(out[jj], w_gate[JB + jj], gp);
    }
}

// --------------------------------------------- fused SpMM hop2 + linear + relu
// Phase A (256 threads, 4 lanes/node, 64 nodes/block): hop-2 gather from Hb;
// result stays in f32 LDS (hc) -- no HC global buffer.
// Interleave (R7): own-node ra/rb row loads issued BEFORE the gather loop;
// the gather-independent 2/3 of the MLP (ha.W0+hb.W1) runs between
// gather-end and the barrier; only hc.W2 + epilogue post-barrier. Wave w
// owns output columns 8w..8w+7 (template literal); lane = node. Hazards:
// ra read pre-barrier / Ha write post-barrier; blocks touch only their own
// 64 Ha rows (hop2 gathers Hb, never Ha) -> race-free.
__global__ __launch_bounds__(256, 4) void spmm_mlp_kernel(
    const unsigned* __restrict__ Hb,     // hop1 result (gather src + MLP input)
    unsigned* __restrict__ Ha,           // layer state (MLP input + output)
    const int* __restrict__ rowbeg,
    const int* __restrict__ rowend,
    const int* __restrict__ col,
    const float* __restrict__ normv,
    const float* __restrict__ invn,
    const float* __restrict__ W,         // this layer's 3*F*F block
    const float* __restrict__ bias,
    float* __restrict__ gatev,
    const float* __restrict__ w_gate,
    const float* __restrict__ b_gate,
    int do_gate, int N)
{
    __shared__ float hcL[64 * 33];       // stride 33: conflict-free both phases
    __shared__ float gred[256];          // gate partials (last layer only)
    const int tid = threadIdx.x;
    const int ln = tid & 63;
    const int wv = tid >> 6;             // wave-uniform
    const int n2 = blockIdx.x * 64 + ln;
    // ---- issue own-node row loads FIRST (fly alongside the gathers)
    uint4 ra[4], rb[4];
    if (n2 < N) {
        const uint4* pa = (const uint4*)(Ha + (size_t)n2 * RSTRIDE);
        const uint4* pb = (const uint4*)(Hb + (size_t)n2 * RSTRIDE);
#pragma unroll
        for (int q = 0; q < 4; ++q) ra[q] = pa[q];
#pragma unroll
        for (int q = 0; q < 4; ++q) rb[q] = pb[q];
    }
    // ---------------- phase A: hop-2 gather -> hcL
    {
        int node = blockIdx.x * 64 + (tid >> 2);
        int sub = tid & 3;
        if (node < N) {
            int s = rowbeg[node];
            int nit = (rowend[node] - s) >> 3;
            float acc0 = 0.f, acc1 = 0.f, acc2 = 0.f, acc3 = 0.f;
            float acc4 = 0.f, acc5 = 0.f, acc6 = 0.f, acc7 = 0.f;
            if (nit > 0) {
                const iv4* cl = (const iv4*)(col + s);
                iv4 ca = __builtin_nontemporal_load(cl);
                iv4 cb = __builtin_nontemporal_load(cl + 1);
                for (int it = 0; it < nit; ++it) {
                    uint4 v0, v1, v2, v3, v4, v5, v6, v7;
                    GATHER8(Hb, v0, v1, v2, v3, v4, v5, v6, v7, ca, cb)
                    const iv4* nx = cl + ((it + 1 < nit) ? 2 : 0);
                    iv4 na = __builtin_nontemporal_load(nx);
                    iv4 nb = __builtin_nontemporal_load(nx + 1);
                    cl += 2;
                    ACC8(v0, v1, v2, v3, v4, v5, v6, v7)
                    ca = na; cb = nb;
                }
            }
            float nv = normv[node];
            float nn2 = nv * nv;
            float* hp = &hcL[(tid >> 2) * 33 + sub * 8];
            hp[0] = nn2 * acc0; hp[1] = nn2 * acc1;
            hp[2] = nn2 * acc2; hp[3] = nn2 * acc3;
            hp[4] = nn2 * acc4; hp[5] = nn2 * acc5;
            hp[6] = nn2 * acc6; hp[7] = nn2 * acc7;
        }
    }
    // ---- pre-barrier MLP: the gather-independent 2/3 (ha.W0 + hb.W1)
    float out[8];
#pragma unroll
    for (int jj = 0; jj < 8; ++jj) out[jj] = 0.0f;
    if (n2 < N) {
        if      (wv == 0) mlp_pre<0,  8>(ra, rb, W, out);
        else if (wv == 1) mlp_pre<8,  8>(ra, rb, W, out);
        else if (wv == 2) mlp_pre<16, 8>(ra, rb, W, out);
        else              mlp_pre<24, 7>(ra, rb, W, out);
    }
    __syncthreads();                      // hcL ready; all Ha reads done
    // ---- post-barrier: hc.W2 + epilogue only
    float gp = 0.0f;
    if (n2 < N) {
        const float* hp = &hcL[ln * 33];
        float inv = invn[n2];
        float sc = do_gate ? 1.0f : normv[n2];       // next layer wants norm-scaled
        unsigned* orow = Ha + (size_t)n2 * RSTRIDE;
        if      (wv == 0) mlp_fin<0,  8>(out, hp, W, bias, inv, sc, orow, w_gate, do_gate, gp);
        else if (wv == 1) mlp_fin<8,  8>(out, hp, W, bias, inv, sc, orow, w_gate, do_gate, gp);
        else if (wv == 2) mlp_fin<16, 8>(out, hp, W, bias, inv, sc, orow, w_gate, do_gate, gp);
        else              mlp_fin<24, 7>(out, hp, W, bias, inv, sc, orow, w_gate, do_gate, gp);
    }
    if (do_gate) {
        gred[tid] = gp;
        __syncthreads();
        if (tid < 64 && n2 < N)
            gatev[n2] = b_gate[0] + gred[tid] + gred[tid + 64] + gred[tid + 128] + gred[tid + 192];
    }
}

// ------------------------------------------------- fused pooling (R8)
// One block per graph: softmax stats (m, den) via wave reduce, then the
// feature-parallel weighted sum, written straight to the padded output slot.
// Pad slots are zeroed by a memset on d_out before this launches.
__global__ __launch_bounds__(64) void gpool_kernel(const unsigned short* __restrict__ H,
                                                   const float* __restrict__ gate,
                                                   const int* __restrict__ gid,
                                                   const int* __restrict__ soff,
                                                   int Bn, int MAXG, int Ntot,
                                                   float* __restrict__ out) {
    int g = blockIdx.x;
    if (g >= soff[Bn]) return;
    int t = threadIdx.x;
    int s = lb_gid(gid, Ntot, g), e = lb_gid(gid, Ntot, g + 1);
    float m = -1e30f;
    for (int n = s + t; n < e; n += 64) m = fmaxf(m, gate[n]);
#pragma unroll
    for (int o = 32; o > 0; o >>= 1) m = fmaxf(m, __shfl_xor(m, o));
    float d = 0.0f;
    for (int n = s + t; n < e; n += 64) d += expf(gate[n] - m);
#pragma unroll
    for (int o = 32; o > 0; o >>= 1) d += __shfl_xor(d, o);
    // sample & slot: largest smp with soff[smp] <= g
    int lo = 0, hi = Bn;
    while (hi - lo > 1) { int mid = (lo + hi) >> 1; if (soff[mid] <= g) lo = mid; else hi = mid; }
    int smp = lo, pos = g - soff[smp];
    if (t >= FDIM) return;
    float acc = 0.0f;
    for (int n = s; n < e; ++n)
        acc += expf(gate[n] - m) * __uint_as_float((unsigned)H[(size_t)n * FPAD + t] << 16);
    out[((size_t)smp * MAXG + pos) * FDIM + t] = acc / d;
}

// ------------------------------------------------------------------ launcher

extern "C" void kernel_launch(void* const* d_in, const int* in_sizes, int n_in,
                              void* d_out, int out_size, void* d_ws, size_t ws_size,
                              hipStream_t stream) {
    const float* x      = (const float*)d_in[0];
    const float* Ws     = (const float*)d_in[1];
    const float* bs     = (const float*)d_in[2];
    const float* w_gate = (const float*)d_in[3];
    const float* b_gate = (const float*)d_in[4];
    const int* src       = (const int*)d_in[5];
    const int* dst       = (const int*)d_in[6];
    const int* graph_ids = (const int*)d_in[7];
    const int* num       = (const int*)d_in[8];
    float* out  = (float*)d_out;

    const int N  = in_sizes[7];
    const int E  = in_sizes[5];
    const int Bn = in_sizes[8];
    const int F  = in_sizes[3];            // 31
    const int L  = in_sizes[2] / F;        // 5
    const int nW = in_sizes[1];            // L * 3F * F
    const int WperL = nW / L;              // 3F*F
    const int MAXG = out_size / (Bn * F);  // 120
    const int Gmax = Bn * MAXG;

    const int nbuk = (N + CW - 1) / CW;    // 196 for N=400K
    const int cap  = E / nbuk + E / (8 * nbuk) + 2048;

    // ---- workspace carve-up
    char* p = (char*)d_ws;
    auto alloc = [&](size_t bytes) {
        void* r = (void*)p;
        p += (bytes + 255) & ~(size_t)255;
        return r;
    };
    // H arrays carry N+1 rows: row N is the all-zero dummy consumed by pad edges
    unsigned* HA = (unsigned*)alloc((size_t)(N + 1) * RSTRIDE * 4);
    unsigned* HB = (unsigned*)alloc((size_t)(N + 1) * RSTRIDE * 4);
    int*   colw  = (int*)alloc(((size_t)E + (size_t)nbuk * (7 * CW + 16)) * 4);  // padded CSR
    int*   bkt   = (int*)alloc((size_t)nbuk * cap * 4);
    int*   gcnt  = (int*)alloc((size_t)nbuk * 4);
    int*   bbase = (int*)alloc((size_t)nbuk * 4);
    int*   rowb  = (int*)alloc((size_t)(N + 1) * 4);
    int*   rowe  = (int*)alloc((size_t)(N + 1) * 4);
    float* normv = (float*)alloc((size_t)N * 4);
    float* invnv = (float*)alloc((size_t)N * 4);
    float* gatev = (float*)alloc((size_t)N * 4);
    int*   soff  = (int*)alloc((size_t)(Bn + 1) * 4);

    // ---- zero init: gcnt + output (gpool writes only real slots)
    (void)hipMemsetAsync(gcnt, 0, (size_t)nbuk * 4, stream);
    (void)hipMemsetAsync(out, 0, (size_t)out_size * 4, stream);

    // ---- CSR build (+fused input cast): multisplit -> scans -> bucket build
    const int NT = (E + TILE - 1) / TILE;
    multisplit_kernel<<<NT, 256, 0, stream>>>(src, dst, gcnt, bkt, cap, E, nbuk);
    small_scans_kernel<<<1, 64, 0, stream>>>(num, soff, Bn, gcnt, bbase, nbuk, cap);
    bucket_build_kernel<<<nbuk, 1024, 0, stream>>>(bkt, gcnt, bbase, rowb, rowe,
                                                   normv, invnv, colw, x, HA,
                                                   cap, N, nbuk);

    // ---- 5 TAGConv layers: hop1 (HA->HB), fused hop2+MLP (HB,HA -> HA in place)
    const int SB  = (N + 1 + 63) / 64;     // +1 covers the dummy zero row
    const int SB2 = (N + 63) / 64;
    for (int l = 0; l < L; ++l) {
        spmm_kernel<<<SB, 256, 0, stream>>>(HA, HB, rowb, rowe, colw, normv, N);
        spmm_mlp_kernel<<<SB2, 256, 0, stream>>>(HB, HA, rowb, rowe, colw, normv, invnv,
                                                 Ws + (size_t)l * WperL, bs + (size_t)l * F,
                                                 gatev, w_gate, b_gate,
                                                 (l == L - 1) ? 1 : 0, N);
    }

    // ---- fused gated attention pooling + padded scatter
    gpool_kernel<<<Gmax, 64, 0, stream>>>((const unsigned short*)HA, gatev, graph_ids,
                                          soff, Bn, MAXG, N, out);
    (void)n_in; (void)ws_size;
}

// Round 9
// 1531.789 us; speedup vs baseline: 1.0462x; 1.0462x over previous
//
#include <hip/hip_runtime.h>
#include <hip/hip_bf16.h>

// Problem constants (F is hard-coded 31 in the reference / TAG)
#define FDIM 31
#define FPAD 32      // padded row length in elements
#define RSTRIDE 16   // row stride in uints (32 bf16 = 64 B = 16 uints = 1 cache line)

// Coarse bucketing for CSR build: 2048 nodes per bucket
#define CBITS 11
#define CW    (1 << CBITS)
#define MAXBUK 256
#define TILE 4096

// clang ext-vector types: required by __builtin_nontemporal_{load,store}
// (HIP_vector_type int4/uint4 pointers are rejected by the builtin).
typedef int      iv4 __attribute__((ext_vector_type(4)));
typedef unsigned uv4 __attribute__((ext_vector_type(4)));

// ---- bf16 pack/unpack helpers (packed as 2 bf16 per uint, little-endian)
__device__ __forceinline__ float bf_lo(unsigned u) { return __uint_as_float(u << 16); }
__device__ __forceinline__ float bf_hi(unsigned u) { return __uint_as_float(u & 0xFFFF0000u); }
__device__ __forceinline__ unsigned pack2(float lo, float hi) {
    unsigned a = __float_as_uint(lo), b = __float_as_uint(hi);
    unsigned ra = (a + 0x7FFFu + ((a >> 16) & 1u)) >> 16;   // RNE
    unsigned rb = (b + 0x7FFFu + ((b >> 16) & 1u)) >> 16;
    return ra | (rb << 16);
}

// first index in sorted gid[0..Ntot) with gid[idx] >= g
__device__ __forceinline__ int lb_gid(const int* __restrict__ gid, int Ntot, int g) {
    int lo = 0, hi = Ntot;
    while (lo < hi) { int mid = (lo + hi) >> 1; if (gid[mid] < g) lo = mid + 1; else hi = mid; }
    return lo;
}

// --------------------------------------------------- multisplit (level 1)
// R9: REVERTED to the R7 staged form. R8's direct-write variant scattered
// 4B stores across 196 bucket cursors -> ~every store hit a distinct 64B
// line -> L2 write-allocate amplified WRITE_SIZE 26->150 MB and the kernel
// went 30->140 us. The ordered[] LDS staging exists precisely so the global
// writes are CONTIGUOUS per bucket segment. Do not remove it again.
__global__ __launch_bounds__(256) void multisplit_kernel(
    const int* __restrict__ src, const int* __restrict__ dst,
    int* __restrict__ gcnt, int* __restrict__ bucketed,
    int cap, int E, int nbuk)
{
    __shared__ int ordered[TILE];
    __shared__ int hist[MAXBUK];
    __shared__ int lofs[MAXBUK + 1];
    __shared__ int base_[MAXBUK];
    __shared__ int cur[MAXBUK];
    const int tid = threadIdx.x;
    const int e0 = blockIdx.x * TILE;
    const int n = min(TILE, E - e0);
    if (tid < MAXBUK) hist[tid] = 0;
    __syncthreads();
    for (int i = tid; i < n; i += 256)
        atomicAdd(&hist[dst[e0 + i] >> CBITS], 1);
    __syncthreads();
    if (tid == 0) {
        int a = 0;
        for (int b = 0; b < nbuk; ++b) { lofs[b] = a; a += hist[b]; }
        lofs[nbuk] = a;
    }
    __syncthreads();
    if (tid < nbuk) {
        int h = hist[tid];
        base_[tid] = h ? atomicAdd(&gcnt[tid], h) : 0;
        cur[tid] = lofs[tid];
    }
    __syncthreads();
    for (int i = tid; i < n; i += 256) {
        int s = src[e0 + i], d = dst[e0 + i];
        int b = d >> CBITS;
        int r = atomicAdd(&cur[b], 1);
        ordered[r] = (s << CBITS) | (d & (CW - 1));
    }
    __syncthreads();
    for (int i = tid; i < n; i += 256) {
        int lo = 0, hi = nbuk;
        while (hi - lo > 1) {
            int mid = (lo + hi) >> 1;
            if (lofs[mid] <= i) lo = mid; else hi = mid;
        }
        int b = lo;
        int pos = base_[b] + (i - lofs[b]);
        if (pos < cap) bucketed[(size_t)b * cap + pos] = ordered[i];
    }
}

// ---------------------------------- small scans: num->soff, gcnt->bbase
// R8: wave-parallel chunked __shfl_up scans (the 1-thread serial loops cost
// ~200 L2-latency-bound iterations). 64-thread block = 1 wave.
__global__ __launch_bounds__(64) void small_scans_kernel(
    const int* __restrict__ num, int* __restrict__ soff, int Bn,
    const int* __restrict__ gcnt, int* __restrict__ bbase, int nbuk, int cap) {
    const int t = threadIdx.x;
    __shared__ int carry;
    if (t == 0) { carry = 0; soff[0] = 0; }
    __syncthreads();
    for (int c0 = 0; c0 < Bn; c0 += 64) {
        int idx = c0 + t;
        int v = (idx < Bn) ? num[idx] : 0;
        int sc = v;
#pragma unroll
        for (int o = 1; o < 64; o <<= 1) { int u = __shfl_up(sc, o); if (t >= o) sc += u; }
        if (idx < Bn) soff[idx + 1] = carry + sc;      // inclusive
        __syncthreads();
        if (t == 63) carry += sc;
        __syncthreads();
    }
    if (t == 0) carry = 0;
    __syncthreads();
    for (int c0 = 0; c0 < nbuk; c0 += 64) {
        int idx = c0 + t;
        int v = (idx < nbuk) ? (((min(gcnt[idx], cap) + 7) & ~7) + 7 * CW) : 0;
        int sc = v;
#pragma unroll
        for (int o = 1; o < 64; o <<= 1) { int u = __shfl_up(sc, o); if (t >= o) sc += u; }
        if (idx < nbuk) bbase[idx] = carry + sc - v;   // exclusive
        __syncthreads();
        if (t == 63) carry += sc;
        __syncthreads();
    }
}

// ------ per-bucket: hist + LDS scan + rowbeg/rowend/normv + CSR fill + CAST
// Rows are padded to a multiple of 8 edges; pad slots point at dummy node N
// (whose feature row is all zeros) so the SpMM loop has NO scalar tail.
// R8: the fp32->bf16 norm-scaled cast of x into HA is fused here (one less
// launch; normv stays in LDS, no global round-trip).
__global__ __launch_bounds__(1024) void bucket_build_kernel(
    const int* __restrict__ bucketed, const int* __restrict__ gcnt,
    const int* __restrict__ bbase,
    int* __restrict__ rowbeg, int* __restrict__ rowend,
    float* __restrict__ normv, float* __restrict__ invn,
    int* __restrict__ col,
    const float* __restrict__ x, unsigned* __restrict__ HA,
    int cap, int N, int nbuk)
{
    __shared__ int hist[CW];     // counts -> padded counts -> inclusive scan
    __shared__ int lcur[CW];     // fill cursors
    __shared__ float nvL[CW];    // norm values for the fused cast
    const int b = blockIdx.x, tid = threadIdx.x;
    hist[tid] = 0; hist[tid + 1024] = 0;
    __syncthreads();
    const int cnt = min(gcnt[b], cap);
    const int* reg = bucketed + (size_t)b * cap;
    for (int i = tid; i < cnt; i += 1024)
        atomicAdd(&hist[reg[i] & (CW - 1)], 1);
    __syncthreads();
    int c0 = hist[tid], c1 = hist[tid + 1024];       // real per-node counts
    int p0 = (c0 + 7) & ~7, p1 = (c1 + 7) & ~7;      // padded to multiple of 8
    __syncthreads();
    hist[tid] = p0; hist[tid + 1024] = p1;           // scan PADDED counts
    __syncthreads();
    // Hillis-Steele inclusive scan over 2048 entries with 1024 threads
    for (int off = 1; off < CW; off <<= 1) {
        int a0 = (tid >= off) ? hist[tid - off] : 0;
        int a1 = (tid + 1024 >= off) ? hist[tid + 1024 - off] : 0;
        __syncthreads();
        hist[tid] += a0; hist[tid + 1024] += a1;
        __syncthreads();
    }
    const int base = bbase[b];
    const int base_node = b << CBITS;
    int r0 = -1, r1 = -1;
    int node = base_node + tid;
    if (node < N) {
        r0 = base + hist[tid] - p0;                  // exclusive padded prefix
        rowbeg[node] = r0; rowend[node] = r0 + p0; lcur[tid] = r0;
        int cr = c0 > 0 ? c0 : 1;
        float nv = rsqrtf((float)cr);
        normv[node] = nv; nvL[tid] = nv;
        invn[node]  = sqrtf((float)cr);
    }
    node = base_node + tid + 1024;
    if (node < N) {
        r1 = base + hist[tid + 1024] - p1;
        rowbeg[node] = r1; rowend[node] = r1 + p1; lcur[tid + 1024] = r1;
        int cr = c1 > 0 ? c1 : 1;
        float nv = rsqrtf((float)cr);
        normv[node] = nv; nvL[tid + 1024] = nv;
        invn[node]  = sqrtf((float)cr);
    }
    __syncthreads();
    for (int i = tid; i < cnt; i += 1024) {
        int e = reg[i];
        int p = atomicAdd(&lcur[e & (CW - 1)], 1);
        col[p] = e >> CBITS;
    }
    // pad slots -> dummy node N (disjoint from real slots: no sync needed)
    if (r0 >= 0) for (int j = r0 + c0; j < r0 + p0; ++j) col[j] = N;
    if (r1 >= 0) for (int j = r1 + c1; j < r1 + p1; ++j) col[j] = N;
    // ---- fused cast: HA[n] = bf16(norm[n] * x[n]) for this bucket's nodes
    // (row N, if in range, is written as zeros -- the pad-gather target)
    __syncthreads();                                 // nvL ready
    const int nodes_here = min(CW, N + 1 - base_node);
    for (int idx = tid; idx < nodes_here * RSTRIDE; idx += 1024) {
        int loc = idx >> 4, q = idx & 15;
        int nodec = base_node + loc;
        unsigned val = 0u;
        if (nodec < N) {
            float nv = nvL[loc];
            int f0 = 2 * q, f1 = 2 * q + 1;
            float lo = (f0 < FDIM) ? nv * x[(size_t)nodec * FDIM + f0] : 0.0f;
            float hi = (f1 < FDIM) ? nv * x[(size_t)nodec * FDIM + f1] : 0.0f;
            val = pack2(lo, hi);
        }
        HA[(size_t)nodec * RSTRIDE + q] = val;
    }
    // safety: if N is a multiple of CW, row N belongs to no bucket
    if (b == nbuk - 1 && base_node + CW <= N)
        for (int q = tid; q < RSTRIDE; q += 1024) HA[(size_t)N * RSTRIDE + q] = 0u;
}

// ---- gather/accumulate macro bodies
#define GATHER8(HSRC, r0, r1, r2, r3, r4, r5, r6, r7, CA, CB)                    \
    r0 = *((const uint4*)(HSRC + (size_t)(CA).x * RSTRIDE) + sub);               \
    r1 = *((const uint4*)(HSRC + (size_t)(CA).y * RSTRIDE) + sub);               \
    r2 = *((const uint4*)(HSRC + (size_t)(CA).z * RSTRIDE) + sub);               \
    r3 = *((const uint4*)(HSRC + (size_t)(CA).w * RSTRIDE) + sub);               \
    r4 = *((const uint4*)(HSRC + (size_t)(CB).x * RSTRIDE) + sub);               \
    r5 = *((const uint4*)(HSRC + (size_t)(CB).y * RSTRIDE) + sub);               \
    r6 = *((const uint4*)(HSRC + (size_t)(CB).z * RSTRIDE) + sub);               \
    r7 = *((const uint4*)(HSRC + (size_t)(CB).w * RSTRIDE) + sub);

#define ACC_EDGE(vN)                                                   \
    acc0 += bf_lo(vN.x); acc1 += bf_hi(vN.x);                          \
    acc2 += bf_lo(vN.y); acc3 += bf_hi(vN.y);                          \
    acc4 += bf_lo(vN.z); acc5 += bf_hi(vN.z);                          \
    acc6 += bf_lo(vN.w); acc7 += bf_hi(vN.w);

#define ACC8(r0, r1, r2, r3, r4, r5, r6, r7)                           \
    ACC_EDGE(r0) ACC_EDGE(r1) ACC_EDGE(r2) ACC_EDGE(r3)                \
    ACC_EDGE(r4) ACC_EDGE(r5) ACC_EDGE(r6) ACC_EDGE(r7)

// ------------------------------------------------------------------ SpMM hop1
// Storage invariant: Hin rows are norm-scaled (H~ = norm .* h), so a hop is
// H~out = norm^2 .* sum(H~in[col]). Rows padded to x8 with dummy node N.
// NOTE (R3/R7 post-mortems): the random gather runs at a ~3.4-3.7 TB/s
// fabric ceiling insensitive to occupancy (47->55%: null), deeper per-wave
// pipelining (2-deep: null), and store cache policy (NT vs normal: null).
// ~113 us is this kernel's floor without a bytes reduction.
__global__ __launch_bounds__(256) void spmm_kernel(const unsigned* __restrict__ Hin,
                                                   unsigned* __restrict__ Hout,
                                                   const int* __restrict__ rowbeg,
                                                   const int* __restrict__ rowend,
                                                   const int* __restrict__ col,
                                                   const float* __restrict__ normv, int N) {
    int node = blockIdx.x * 64 + (threadIdx.x >> 2);
    int sub = threadIdx.x & 3;
    if (node > N) return;
    if (node == N) {                       // dummy zero row consumed by pad edges
        uint4 z; z.x = z.y = z.z = z.w = 0u;
        *((uint4*)(Hout + (size_t)N * RSTRIDE) + sub) = z;
        return;
    }
    int s = rowbeg[node];
    int nit = (rowend[node] - s) >> 3;
    float acc0 = 0.f, acc1 = 0.f, acc2 = 0.f, acc3 = 0.f;
    float acc4 = 0.f, acc5 = 0.f, acc6 = 0.f, acc7 = 0.f;
    if (nit > 0) {
        const iv4* cl = (const iv4*)(col + s);      // 16B-aligned (rows 8-aligned)
        iv4 ca = __builtin_nontemporal_load(cl);
        iv4 cb = __builtin_nontemporal_load(cl + 1);
        for (int it = 0; it < nit; ++it) {
            uint4 v0, v1, v2, v3, v4, v5, v6, v7;
            GATHER8(Hin, v0, v1, v2, v3, v4, v5, v6, v7, ca, cb)
            const iv4* nx = cl + ((it + 1 < nit) ? 2 : 0);
            iv4 na = __builtin_nontemporal_load(nx);
            iv4 nb = __builtin_nontemporal_load(nx + 1);
            cl += 2;
            ACC8(v0, v1, v2, v3, v4, v5, v6, v7)
            ca = na; cb = nb;
        }
    }
    float nv = normv[node];
    float nn2 = nv * nv;                   // H~out = norm^2 * sum
    uint4 o;
    o.x = pack2(nn2 * acc0, nn2 * acc1);
    o.y = pack2(nn2 * acc2, nn2 * acc3);
    o.z = pack2(nn2 * acc4, nn2 * acc5);
    o.w = pack2(nn2 * acc6, nn2 * acc7);
    *((uint4*)(Hout + (size_t)node * RSTRIDE) + sub) = o;
}

// ---- phase-B workers. JB/NJ are TEMPLATE LITERALS so every W/bias/w_gate
// index is a compile-time offset from a uniform pointer -> provably uniform
// -> s_load. (R5 post-mortem: runtime readfirstlane + clamp broke uniformity
// analysis -> per-lane VMEM W loads -> VALU x2, gather BW -33%.)
// R7 split: mlp_pre (ha.W0 + hb.W1 -- independent of the gather) runs BEFORE
// the barrier, overlapping other waves' gathers; mlp_fin (hc.W2 + epilogue)
// is the only post-barrier work (~1/3 of the FMAs).
template<int JB, int NJ>
__device__ __forceinline__ void mlp_pre(const uint4 (&ra)[4], const uint4 (&rb)[4],
                                        const float* __restrict__ W, float (&out)[8]) {
    const unsigned* ru = (const unsigned*)ra;
    const unsigned* rv = (const unsigned*)rb;
#pragma unroll
    for (int i = 0; i < FDIM; ++i) {
        float va = (i & 1) ? bf_hi(ru[i >> 1]) : bf_lo(ru[i >> 1]);
        float vb = (i & 1) ? bf_hi(rv[i >> 1]) : bf_lo(rv[i >> 1]);
#pragma unroll
        for (int jj = 0; jj < NJ; ++jj) {
            out[jj] = fmaf(va, W[i * FDIM + JB + jj], out[jj]);
            out[jj] = fmaf(vb, W[FDIM * FDIM + i * FDIM + JB + jj], out[jj]);
        }
    }
}

template<int JB, int NJ>
__device__ __forceinline__ void mlp_fin(float (&out)[8], const float* hp,
                                        const float* __restrict__ W,
                                        const float* __restrict__ bias,
                                        float inv, float sc, unsigned* orow,
                                        const float* __restrict__ w_gate,
                                        int do_gate, float& gp) {
#pragma unroll
    for (int i = 0; i < FDIM; ++i) {
        float v = hp[i];
#pragma unroll
        for (int jj = 0; jj < NJ; ++jj)
            out[jj] = fmaf(v, W[2 * FDIM * FDIM + i * FDIM + JB + jj], out[jj]);
    }
#pragma unroll
    for (int jj = 0; jj < NJ; ++jj)
        out[jj] = fmaxf(fmaf(out[jj], inv, bias[JB + jj]), 0.0f);
#pragma unroll
    for (int jj = NJ; jj < 8; ++jj) out[jj] = 0.0f;  // pad column (wave 3)
    uint4 q;
    q.x = pack2(sc * out[0], sc * out[1]);
    q.y = pack2(sc * out[2], sc * out[3]);
    q.z = pack2(sc * out[4], sc * out[5]);
    q.w = pack2(sc * out[6], sc * out[7]);
    ((uint4*)orow)[JB >> 3] = q;                     // disjoint 16B quarter
    if (do_gate) {
#pragma unroll
        for (int jj = 0; jj < NJ; ++jj)
            gp = fmaf(out[jj], w_gate[JB + jj], gp);
    }
}

// --------------------------------------------- fused SpMM hop2 + linear + relu
// Phase A (256 threads, 4 lanes/node, 64 nodes/block): hop-2 gather from Hb;
// result stays in f32 LDS (hc) -- no HC global buffer.
// Interleave (R7): own-node ra/rb row loads issued BEFORE the gather loop;
// the gather-independent 2/3 of the MLP (ha.W0+hb.W1) runs between
// gather-end and the barrier; only hc.W2 + epilogue post-barrier. Wave w
// owns output columns 8w..8w+7 (template literal); lane = node. Hazards:
// ra read pre-barrier / Ha write post-barrier; blocks touch only their own
// 64 Ha rows (hop2 gathers Hb, never Ha) -> race-free.
__global__ __launch_bounds__(256, 4) void spmm_mlp_kernel(
    const unsigned* __restrict__ Hb,     // hop1 result (gather src + MLP input)
    unsigned* __restrict__ Ha,           // layer state (MLP input + output)
    const int* __restrict__ rowbeg,
    const int* __restrict__ rowend,
    const int* __restrict__ col,
    const float* __restrict__ normv,
    const float* __restrict__ invn,
    const float* __restrict__ W,         // this layer's 3*F*F block
    const float* __restrict__ bias,
    float* __restrict__ gatev,
    const float* __restrict__ w_gate,
    const float* __restrict__ b_gate,
    int do_gate, int N)
{
    __shared__ float hcL[64 * 33];       // stride 33: conflict-free both phases
    __shared__ float gred[256];          // gate partials (last layer only)
    const int tid = threadIdx.x;
    const int ln = tid & 63;
    const int wv = tid >> 6;             // wave-uniform
    const int n2 = blockIdx.x * 64 + ln;
    // ---- issue own-node row loads FIRST (fly alongside the gathers)
    uint4 ra[4], rb[4];
    if (n2 < N) {
        const uint4* pa = (const uint4*)(Ha + (size_t)n2 * RSTRIDE);
        const uint4* pb = (const uint4*)(Hb + (size_t)n2 * RSTRIDE);
#pragma unroll
        for (int q = 0; q < 4; ++q) ra[q] = pa[q];
#pragma unroll
        for (int q = 0; q < 4; ++q) rb[q] = pb[q];
    }
    // ---------------- phase A: hop-2 gather -> hcL
    {
        int node = blockIdx.x * 64 + (tid >> 2);
        int sub = tid & 3;
        if (node < N) {
            int s = rowbeg[node];
            int nit = (rowend[node] - s) >> 3;
            float acc0 = 0.f, acc1 = 0.f, acc2 = 0.f, acc3 = 0.f;
            float acc4 = 0.f, acc5 = 0.f, acc6 = 0.f, acc7 = 0.f;
            if (nit > 0) {
                const iv4* cl = (const iv4*)(col + s);
                iv4 ca = __builtin_nontemporal_load(cl);
                iv4 cb = __builtin_nontemporal_load(cl + 1);
                for (int it = 0; it < nit; ++it) {
                    uint4 v0, v1, v2, v3, v4, v5, v6, v7;
                    GATHER8(Hb, v0, v1, v2, v3, v4, v5, v6, v7, ca, cb)
                    const iv4* nx = cl + ((it + 1 < nit) ? 2 : 0);
                    iv4 na = __builtin_nontemporal_load(nx);
                    iv4 nb = __builtin_nontemporal_load(nx + 1);
                    cl += 2;
                    ACC8(v0, v1, v2, v3, v4, v5, v6, v7)
                    ca = na; cb = nb;
                }
            }
            float nv = normv[node];
            float nn2 = nv * nv;
            float* hp = &hcL[(tid >> 2) * 33 + sub * 8];
            hp[0] = nn2 * acc0; hp[1] = nn2 * acc1;
            hp[2] = nn2 * acc2; hp[3] = nn2 * acc3;
            hp[4] = nn2 * acc4; hp[5] = nn2 * acc5;
            hp[6] = nn2 * acc6; hp[7] = nn2 * acc7;
        }
    }
    // ---- pre-barrier MLP: the gather-independent 2/3 (ha.W0 + hb.W1)
    float out[8];
#pragma unroll
    for (int jj = 0; jj < 8; ++jj) out[jj] = 0.0f;
    if (n2 < N) {
        if      (wv == 0) mlp_pre<0,  8>(ra, rb, W, out);
        else if (wv == 1) mlp_pre<8,  8>(ra, rb, W, out);
        else if (wv == 2) mlp_pre<16, 8>(ra, rb, W, out);
        else              mlp_pre<24, 7>(ra, rb, W, out);
    }
    __syncthreads();                      // hcL ready; all Ha reads done
    // ---- post-barrier: hc.W2 + epilogue only
    float gp = 0.0f;
    if (n2 < N) {
        const float* hp = &hcL[ln * 33];
        float inv = invn[n2];
        float sc = do_gate ? 1.0f : normv[n2];       // next layer wants norm-scaled
        unsigned* orow = Ha + (size_t)n2 * RSTRIDE;
        if      (wv == 0) mlp_fin<0,  8>(out, hp, W, bias, inv, sc, orow, w_gate, do_gate, gp);
        else if (wv == 1) mlp_fin<8,  8>(out, hp, W, bias, inv, sc, orow, w_gate, do_gate, gp);
        else if (wv == 2) mlp_fin<16, 8>(out, hp, W, bias, inv, sc, orow, w_gate, do_gate, gp);
        else              mlp_fin<24, 7>(out, hp, W, bias, inv, sc, orow, w_gate, do_gate, gp);
    }
    if (do_gate) {
        gred[tid] = gp;
        __syncthreads();
        if (tid < 64 && n2 < N)
            gatev[n2] = b_gate[0] + gred[tid] + gred[tid + 64] + gred[tid + 128] + gred[tid + 192];
    }
}

// ------------------------------------------------- fused pooling (R8)
// One block per graph: softmax stats (m, den) via wave reduce, then the
// feature-parallel weighted sum, written straight to the padded output slot.
// Pad slots are zeroed by a memset on d_out before this launches.
__global__ __launch_bounds__(64) void gpool_kernel(const unsigned short* __restrict__ H,
                                                   const float* __restrict__ gate,
                                                   const int* __restrict__ gid,
                                                   const int* __restrict__ soff,
                                                   int Bn, int MAXG, int Ntot,
                                                   float* __restrict__ out) {
    int g = blockIdx.x;
    if (g >= soff[Bn]) return;
    int t = threadIdx.x;
    int s = lb_gid(gid, Ntot, g), e = lb_gid(gid, Ntot, g + 1);
    float m = -1e30f;
    for (int n = s + t; n < e; n += 64) m = fmaxf(m, gate[n]);
#pragma unroll
    for (int o = 32; o > 0; o >>= 1) m = fmaxf(m, __shfl_xor(m, o));
    float d = 0.0f;
    for (int n = s + t; n < e; n += 64) d += expf(gate[n] - m);
#pragma unroll
    for (int o = 32; o > 0; o >>= 1) d += __shfl_xor(d, o);
    // sample & slot: largest smp with soff[smp] <= g
    int lo = 0, hi = Bn;
    while (hi - lo > 1) { int mid = (lo + hi) >> 1; if (soff[mid] <= g) lo = mid; else hi = mid; }
    int smp = lo, pos = g - soff[smp];
    if (t >= FDIM) return;
    float acc = 0.0f;
    for (int n = s; n < e; ++n)
        acc += expf(gate[n] - m) * __uint_as_float((unsigned)H[(size_t)n * FPAD + t] << 16);
    out[((size_t)smp * MAXG + pos) * FDIM + t] = acc / d;
}

// ------------------------------------------------------------------ launcher

extern "C" void kernel_launch(void* const* d_in, const int* in_sizes, int n_in,
                              void* d_out, int out_size, void* d_ws, size_t ws_size,
                              hipStream_t stream) {
    const float* x      = (const float*)d_in[0];
    const float* Ws     = (const float*)d_in[1];
    const float* bs     = (const float*)d_in[2];
    const float* w_gate = (const float*)d_in[3];
    const float* b_gate = (const float*)d_in[4];
    const int* src       = (const int*)d_in[5];
    const int* dst       = (const int*)d_in[6];
    const int* graph_ids = (const int*)d_in[7];
    const int* num       = (const int*)d_in[8];
    float* out  = (float*)d_out;

    const int N  = in_sizes[7];
    const int E  = in_sizes[5];
    const int Bn = in_sizes[8];
    const int F  = in_sizes[3];            // 31
    const int L  = in_sizes[2] / F;        // 5
    const int nW = in_sizes[1];            // L * 3F * F
    const int WperL = nW / L;              // 3F*F
    const int MAXG = out_size / (Bn * F);  // 120
    const int Gmax = Bn * MAXG;

    const int nbuk = (N + CW - 1) / CW;    // 196 for N=400K
    const int cap  = E / nbuk + E / (8 * nbuk) + 2048;

    // ---- workspace carve-up
    char* p = (char*)d_ws;
    auto alloc = [&](size_t bytes) {
        void* r = (void*)p;
        p += (bytes + 255) & ~(size_t)255;
        return r;
    };
    // H arrays carry N+1 rows: row N is the all-zero dummy consumed by pad edges
    unsigned* HA = (unsigned*)alloc((size_t)(N + 1) * RSTRIDE * 4);
    unsigned* HB = (unsigned*)alloc((size_t)(N + 1) * RSTRIDE * 4);
    int*   colw  = (int*)alloc(((size_t)E + (size_t)nbuk * (7 * CW + 16)) * 4);  // padded CSR
    int*   bkt   = (int*)alloc((size_t)nbuk * cap * 4);
    int*   gcnt  = (int*)alloc((size_t)nbuk * 4);
    int*   bbase = (int*)alloc((size_t)nbuk * 4);
    int*   rowb  = (int*)alloc((size_t)(N + 1) * 4);
    int*   rowe  = (int*)alloc((size_t)(N + 1) * 4);
    float* normv = (float*)alloc((size_t)N * 4);
    float* invnv = (float*)alloc((size_t)N * 4);
    float* gatev = (float*)alloc((size_t)N * 4);
    int*   soff  = (int*)alloc((size_t)(Bn + 1) * 4);

    // ---- zero init: gcnt + output (gpool writes only real slots)
    (void)hipMemsetAsync(gcnt, 0, (size_t)nbuk * 4, stream);
    (void)hipMemsetAsync(out, 0, (size_t)out_size * 4, stream);

    // ---- CSR build (+fused input cast): multisplit -> scans -> bucket build
    const int NT = (E + TILE - 1) / TILE;
    multisplit_kernel<<<NT, 256, 0, stream>>>(src, dst, gcnt, bkt, cap, E, nbuk);
    small_scans_kernel<<<1, 64, 0, stream>>>(num, soff, Bn, gcnt, bbase, nbuk, cap);
    bucket_build_kernel<<<nbuk, 1024, 0, stream>>>(bkt, gcnt, bbase, rowb, rowe,
                                                   normv, invnv, colw, x, HA,
                                                   cap, N, nbuk);

    // ---- 5 TAGConv layers: hop1 (HA->HB), fused hop2+MLP (HB,HA -> HA in place)
    const int SB  = (N + 1 + 63) / 64;     // +1 covers the dummy zero row
    const int SB2 = (N + 63) / 64;
    for (int l = 0; l < L; ++l) {
        spmm_kernel<<<SB, 256, 0, stream>>>(HA, HB, rowb, rowe, colw, normv, N);
        spmm_mlp_kernel<<<SB2, 256, 0, stream>>>(HB, HA, rowb, rowe, colw, normv, invnv,
                                                 Ws + (size_t)l * WperL, bs + (size_t)l * F,
                                                 gatev, w_gate, b_gate,
                                                 (l == L - 1) ? 1 : 0, N);
    }

    // ---- fused gated attention pooling + padded scatter
    gpool_kernel<<<Gmax, 64, 0, stream>>>((const unsigned short*)HA, gatev, graph_ids,
                                          soff, Bn, MAXG, N, out);
    (void)n_in; (void)ws_size;
}